// Round 9
// baseline (281.274 us; speedup 1.0000x reference)
//
#include <hip/hip_runtime.h>
#include <math.h>

#define S 1024
#define RADIUS 512
#define NIMG 32   // 16 "output" images then 16 "target" images

// ---------------------------------------------------------------------------
// Complex helpers
// ---------------------------------------------------------------------------
__device__ __forceinline__ float2 cmul(float2 a, float2 b) {
    return make_float2(a.x * b.x - a.y * b.y, a.x * b.y + a.y * b.x);
}
__device__ __forceinline__ float2 cadd(float2 a, float2 b) { return make_float2(a.x + b.x, a.y + b.y); }
__device__ __forceinline__ float2 csub(float2 a, float2 b) { return make_float2(a.x - b.x, a.y - b.y); }

// W_16^k, k=0..7
__device__ const float2 C16[8] = {
    {1.0f, 0.0f},
    {0.92387953251128674f, -0.38268343236508978f},
    {0.70710678118654757f, -0.70710678118654746f},
    {0.38268343236508984f, -0.92387953251128674f},
    {0.0f, -1.0f},
    {-0.38268343236508973f, -0.92387953251128674f},
    {-0.70710678118654746f, -0.70710678118654757f},
    {-0.92387953251128663f, -0.38268343236508989f},
};
// W_8^k, k=0..3
__device__ const float2 C8T[4] = {
    {1.0f, 0.0f},
    {0.70710678118654757f, -0.70710678118654746f},
    {0.0f, -1.0f},
    {-0.70710678118654746f, -0.70710678118654757f},
};
// W512^m, m=0..7
__device__ const float2 W512T[8] = {
    {1.0f, 0.0f},
    {0.99992470183914454f, -0.012271538285719925f},
    {0.99969881869620425f, -0.024541228522912288f},
    {0.99932238458834954f, -0.036807222941358832f},
    {0.99879545620517241f, -0.049067674327418015f},
    {0.99811811290014918f, -0.061320736302208578f},
    {0.99729045667869021f, -0.073564563599667426f},
    {0.99631261218277800f, -0.085797312344439894f},
};
// W64^k, k=0..7
__device__ const float2 W64T[8] = {
    {1.0f, 0.0f},
    {0.99518472667219693f, -0.098017140329560604f},
    {0.98078528040323044f, -0.19509032201612825f},
    {0.95694033573220886f, -0.29028467725446233f},
    {0.92387953251128674f, -0.38268343236508978f},
    {0.88192126434835505f, -0.47139673682599764f},
    {0.83146961230254524f, -0.55557023301960218f},
    {0.77301045336273699f, -0.63439328416364549f},
};
// W128^h (plain order), h=0..7
__device__ const float2 W128P[8] = {
    {1.0f, 0.0f},
    {0.99879545620517241f, -0.049067674327418015f},
    {0.99518472667219693f, -0.098017140329560604f},
    {0.98917650996478101f, -0.14673047445536175f},
    {0.98078528040323044f, -0.19509032201612825f},
    {0.97003125319454397f, -0.24298017990326390f},
    {0.95694033573220886f, -0.29028467725446233f},
    {0.94154406518302081f, -0.33688985339222005f},
};
// W1024^l (plain order), l=0..7
__device__ const float2 W1024P[8] = {
    {1.0f, 0.0f},
    {0.99998117528260111f, -0.0061358846491544753f},
    {0.99992470183914454f, -0.012271538285719925f},
    {0.99983058179582340f, -0.018406729905804820f},
    {0.99969881869620425f, -0.024541228522912288f},
    {0.99952941750109314f, -0.030674803176636626f},
    {0.99932238458834954f, -0.036807222941358832f},
    {0.99907772775264536f, -0.042938256934940820f},
};

// 4 radix-2 DIF stages over 16 register elements (pass A)
__device__ __forceinline__ void fft16(float2 r[16], float2 T) {
    float2 tc[8];
    #pragma unroll
    for (int u = 0; u < 8; ++u) tc[u] = cmul(T, C16[u]);
    #pragma unroll
    for (int u = 0; u < 8; ++u) {
        float2 a = r[u], b = r[u + 8];
        r[u] = cadd(a, b);
        r[u + 8] = cmul(csub(a, b), tc[u]);
    }
    T = cmul(T, T);
    #pragma unroll
    for (int u = 0; u < 4; ++u) tc[u] = cmul(T, C16[2 * u]);
    #pragma unroll
    for (int g = 0; g < 2; ++g)
        #pragma unroll
        for (int u = 0; u < 4; ++u) {
            int lo = g * 8 + u;
            float2 a = r[lo], b = r[lo + 4];
            r[lo] = cadd(a, b);
            r[lo + 4] = cmul(csub(a, b), tc[u]);
        }
    T = cmul(T, T);
    #pragma unroll
    for (int u = 0; u < 2; ++u) tc[u] = cmul(T, C16[4 * u]);
    #pragma unroll
    for (int g = 0; g < 4; ++g)
        #pragma unroll
        for (int u = 0; u < 2; ++u) {
            int lo = g * 4 + u;
            float2 a = r[lo], b = r[lo + 2];
            r[lo] = cadd(a, b);
            r[lo + 2] = cmul(csub(a, b), tc[u]);
        }
    T = cmul(T, T);
    #pragma unroll
    for (int g = 0; g < 8; ++g) {
        int lo = g * 2;
        float2 a = r[lo], b = r[lo + 1];
        r[lo] = cadd(a, b);
        r[lo + 1] = cmul(csub(a, b), T);
    }
}

// 3 radix-2 DIF stages over 8 register elements
__device__ __forceinline__ void fft8(float2 r[8], float2 T) {
    float2 tc[4];
    #pragma unroll
    for (int u = 0; u < 4; ++u) tc[u] = cmul(T, C8T[u]);
    #pragma unroll
    for (int u = 0; u < 4; ++u) {
        float2 a = r[u], b = r[u + 4];
        r[u] = cadd(a, b);
        r[u + 4] = cmul(csub(a, b), tc[u]);
    }
    T = cmul(T, T);
    #pragma unroll
    for (int u = 0; u < 2; ++u) tc[u] = cmul(T, C8T[2 * u]);
    #pragma unroll
    for (int g = 0; g < 2; ++g)
        #pragma unroll
        for (int u = 0; u < 2; ++u) {
            int lo = g * 4 + u;
            float2 a = r[lo], b = r[lo + 2];
            r[lo] = cadd(a, b);
            r[lo + 2] = cmul(csub(a, b), tc[u]);
        }
    T = cmul(T, T);
    #pragma unroll
    for (int g = 0; g < 4; ++g) {
        int lo = g * 2;
        float2 a = r[lo], b = r[lo + 1];
        r[lo] = cadd(a, b);
        r[lo + 1] = cmul(csub(a, b), T);
    }
}

// Last 2 DIF stages (1024-pt, pass A): quad-perm shuffles across c = tau&3
__device__ __forceinline__ void fft_last2(float2 r[16], int c) {
    #pragma unroll
    for (int m = 0; m < 16; ++m) {
        float vx = __shfl_xor(r[m].x, 2, 64);
        float vy = __shfl_xor(r[m].y, 2, 64);
        if (c & 2) {
            float dx = vx - r[m].x, dy = vy - r[m].y;
            if (c & 1) { r[m].x = dy; r[m].y = -dx; }
            else       { r[m].x = dx; r[m].y = dy; }
        } else {
            r[m].x += vx; r[m].y += vy;
        }
    }
    #pragma unroll
    for (int m = 0; m < 16; ++m) {
        float vx = __shfl_xor(r[m].x, 1, 64);
        float vy = __shfl_xor(r[m].y, 1, 64);
        if (c & 1) { r[m].x = vx - r[m].x; r[m].y = vy - r[m].y; }
        else       { r[m].x += vx; r[m].y += vy; }
    }
}

// Swizzled LDS addr for 1024-pt transpose (pass A)
__device__ __forceinline__ int A1x(int n) {
    int j = n >> 6;
    return (n & ~63) | ((n & 63) ^ (j << 2));
}

__device__ __forceinline__ int bitrev3(int x) {
    return ((x & 1) << 2) | (x & 2) | ((x >> 2) & 1);
}

// ---------------------------------------------------------------------------
// Pass A: packed row-pair FFTs (unchanged — validated).
// ---------------------------------------------------------------------------
__global__ __launch_bounds__(512)
void fft_rows(const float* __restrict__ outp, const float* __restrict__ tgtp,
              float2* __restrict__ WpT, int imgBase) {
    __shared__ float2 buf[8 * 1024];
    const int t = threadIdx.x;
    const int w = t >> 6, tau = t & 63;
    const int yy = blockIdx.x * 8 + w;
    const int i = blockIdx.y, g = imgBase + i;
    const float* img = (g < 16 ? outp : tgtp) + (size_t)(g & 15) * S * S;
    const float* r0 = img + (size_t)(2 * yy) * S;
    const float* r1 = r0 + S;

    float2 r[16];
    #pragma unroll
    for (int j = 0; j < 16; ++j) r[j] = make_float2(r0[64 * j + tau], r1[64 * j + tau]);

    float2 T;
    { float sv, cv; sincosf(-6.283185307179586f * (float)tau / 1024.0f, &sv, &cv); T = make_float2(cv, sv); }
    fft16(r, T);

    float2* mybuf = buf + (w << 10);
    #pragma unroll
    for (int j = 0; j < 16; ++j) mybuf[A1x(64 * j + tau)] = r[j];
    const int b = tau >> 2, c = tau & 3;
    #pragma unroll
    for (int m = 0; m < 16; ++m) r[m] = mybuf[(b << 6) + 4 * (m ^ b) + c];

    { float sv, cv; sincosf(-6.283185307179586f * (float)c / 64.0f, &sv, &cv); T = make_float2(cv, sv); }
    fft16(r, T);
    fft_last2(r, c);

    #pragma unroll
    for (int m = 0; m < 16; ++m) {
        int n = (b << 6) + 4 * m + c;
        int k = (int)(__brev((unsigned)n) >> 22);
        mybuf[k ^ (w << 1)] = r[m];
    }
    __syncthreads();

    const int yy0 = blockIdx.x * 8;
    float2* dst = WpT + (size_t)i * 512 * 1024;
    #pragma unroll
    for (int q = 0; q < 16; ++q) {
        int idx = q * 512 + t;
        int uu = idx >> 3, wv = idx & 7;
        float2 val = buf[(wv << 10) | (uu ^ (wv << 1))];
        dst[(size_t)uu * 512 + yy0 + wv] = val;
    }
}

// ---------------------------------------------------------------------------
// Pass B1 (ROUND 9 ablation split): round-8's validated split-wave FFT, NO
// binning. Publishes spectra in NATURAL-f order (bijective, conflict-free),
// combines Gp/Gm with pure-table twiddles, stores |G|^2 to a full 1024x1024
// power image P (direct + conjugate-mirror write; idempotent at u=0,512).
// ---------------------------------------------------------------------------
__global__ __launch_bounds__(512, 4)
void fft_cols_store(const float2* __restrict__ WpT, float* __restrict__ P, int imgBase) {
    __shared__ float2 tbuf[8 * 512];          // 32 KB: 512-slot buffer per wave
    const int t = threadIdx.x;
    const int w = t >> 6, tau = t & 63;
    const int i = blockIdx.y;
    const int u = blockIdx.x * 4 + (w >> 1);  // 4 u-values per block
    const int setb = w & 1;                   // 0: X0 FFT, 1: X1 FFT
    const bool active = (u <= 512);

    const int b3 = tau >> 3, lam = tau & 7;
    float2 X[8];
    float2* mb = tbuf + (w << 9);

    if (active) {
        const float2* Wimg = WpT + (size_t)i * 512 * 1024;
        const int mu = (1024 - u) & 1023;
        const float2* rowA = Wimg + (size_t)u * 512;
        const float2* rowM = Wimg + (size_t)mu * 512;

        #pragma unroll
        for (int j = 0; j < 8; ++j) {
            float2 A = rowA[64 * j + tau];
            float2 M = rowM[64 * j + tau];
            X[j] = (setb == 0)
                 ? make_float2(0.5f * (A.x + M.x), 0.5f * (A.y - M.y))
                 : make_float2(0.5f * (A.y + M.y), 0.5f * (M.x - A.x));
        }

        // Phase 1; T = W512^tau = W64^{b3} * W512^{lam}
        fft8(X, cmul(W64T[b3], W512T[lam]));

        // Transpose 1 (wave-private, swizzled, conflict-free)
        #pragma unroll
        for (int j = 0; j < 8; ++j) mb[(j << 6) | (tau ^ (j << 3) ^ j)] = X[j];
        #pragma unroll
        for (int c = 0; c < 8; ++c) X[c] = mb[(b3 << 6) | (((c ^ b3) << 3) | (lam ^ b3))];

        // Phase 2; T = W64^{lam}
        fft8(X, W64T[lam]);

        // Transpose 2
        #pragma unroll
        for (int c = 0; c < 8; ++c) mb[(b3 << 6) | (((c ^ b3) << 3) | (lam ^ b3))] = X[c];
        #pragma unroll
        for (int d = 0; d < 8; ++d) X[d] = mb[(b3 << 6) | (((lam ^ b3) << 3) | (d ^ b3))];

        // Phase 3 (T = 1)
        fft8(X, make_float2(1.0f, 0.0f));

        // Publish in NATURAL-f order: X[d] is freq f = 64*rev3(d) + 8*rev3(lam) + rev3(b3).
        // For fixed d, (8*rev3(lam)+rev3(b3)) is a bijection over 0..63 -> conflict-free.
        const int base9 = 8 * bitrev3(lam) + bitrev3(b3);
        #pragma unroll
        for (int d = 0; d < 8; ++d) {
            mb[(bitrev3(d) << 6) + base9] = X[d];
        }
    }
    __syncthreads();   // cross-wave exchange (all threads reach this)

    if (active) {
        const float2* b0 = tbuf + ((w & ~1) << 9);   // X0-hat, natural-f
        const float2* b1 = tbuf + ((w | 1) << 9);    // X1-hat, natural-f
        // W1024^tau = W128^{tau>>3} * W1024^{tau&7}
        const float2 Wtau = cmul(W128P[tau >> 3], W1024P[tau & 7]);
        float* Pimg = P + (size_t)i * 1024 * 1024;
        const int um = (1024 - u) & 1023;

        #pragma unroll
        for (int m = 0; m < 8; ++m) {
            const int f = tau + 64 * m;
            float2 x0 = b0[f];
            float2 x1 = b1[f];
            float2 Wf = cmul(Wtau, C16[m]);          // W1024^f
            float2 wx = cmul(Wf, x1);
            float2 G = (setb == 0) ? cadd(x0, wx)    // v = f
                                   : csub(x0, wx);   // v = f + 512
            float p = G.x * G.x + G.y * G.y;
            const int v = f + (setb << 9);
            Pimg[(size_t)u * 1024 + v] = p;
            const int vm = (1024 - v) & 1023;        // conjugate mirror
            Pimg[(size_t)um * 1024 + vm] = p;        // idempotent at u=0,512
        }
    }
}

// ---------------------------------------------------------------------------
// Pass B2: ring gather + reduce. Block = (ring r, image). For each u-column,
// the v-window of ring r is cv in [sqrt(r^2-cu^2), sqrt((r+1)^2-cu^2)).
// cu^2, cv^2, r^2 are EXACT in f32 (quarter-integers < 2^20) and cu^2+cv^2 is
// a half-integer (never an integer square), so window membership matches the
// reference floor(sqrt(...)) bit-for-bit, and adjacent rings tile exactly
// (shared boundary is the identical float). NO atomics anywhere.
// ---------------------------------------------------------------------------
__global__ __launch_bounds__(256)
void bin_rings(const float* __restrict__ P, float* __restrict__ rad, int imgBase) {
    __shared__ float red[256];
    const int r = blockIdx.x;
    const int i = blockIdx.y, g = imgBase + i;
    const float* Pimg = P + (size_t)i * 1024 * 1024;
    const float r2  = (float)(r * r);
    const float r12 = (float)((r + 1) * (r + 1));

    float acc = 0.0f;
    for (int u = threadIdx.x; u < 1024; u += 256) {
        float cu = (u < 512) ? (u + 0.5f) : (u - 1023.5f);
        float cu2 = cu * cu;                  // exact in f32
        float Bv = r12 - cu2;                 // exact
        if (Bv <= 0.0f) continue;
        float Av = r2 - cu2;                  // exact
        float cvlo = (Av > 0.0f) ? sqrtf(Av) : 0.0f;
        float cvhi = sqrtf(Bv);
        int vlo = (int)ceilf(cvlo - 0.5f);    // first v with v+0.5 >= cvlo
        int vhi = (int)ceilf(cvhi - 0.5f);    // first v with v+0.5 >= cvhi
        if (vhi > 512) vhi = 512;
        if (vlo < 0) vlo = 0;
        const float* row = Pimg + (size_t)u * 1024;
        for (int v = vlo; v < vhi; ++v) {
            acc += row[v] + row[1023 - v];    // positive-cv and negative-cv pixels
        }
    }

    red[threadIdx.x] = acc;
    __syncthreads();
    for (int off = 128; off > 0; off >>= 1) {
        if (threadIdx.x < off) red[threadIdx.x] += red[threadIdx.x + off];
        __syncthreads();
    }
    if (threadIdx.x == 0) rad[(size_t)g * RADIUS + r] = red[0];
}

// ---------------------------------------------------------------------------
// Final: loss = mean(|rad_out - rad_tgt|) / S^2
// ---------------------------------------------------------------------------
__global__ __launch_bounds__(256)
void final_loss(const float* __restrict__ rad, float* __restrict__ out) {
    __shared__ float red[256];
    const int t = threadIdx.x;
    float acc = 0.0f;
    for (int i = t; i < 16 * RADIUS; i += 256) {
        int bb = i >> 9;
        int rr = i & (RADIUS - 1);
        float o = rad[(size_t)bb * RADIUS + rr];
        float gg = rad[(size_t)(bb + 16) * RADIUS + rr];
        acc += fabsf(o - gg);
    }
    red[t] = acc;
    __syncthreads();
    for (int off = 128; off > 0; off >>= 1) {
        if (t < off) red[t] += red[t + off];
        __syncthreads();
    }
    if (t == 0) {
        out[0] = red[0] / ((float)S * (float)S) / (16.0f * (float)RADIUS);
    }
}

extern "C" void kernel_launch(void* const* d_in, const int* in_sizes, int n_in,
                              void* d_out, int out_size, void* d_ws, size_t ws_size,
                              hipStream_t stream) {
    const float* outp = (const float*)d_in[0];
    const float* tgtp = (const float*)d_in[1];
    float* dout = (float*)d_out;

    char* ws = (char*)d_ws;
    float* rad = (float*)ws;                                  // 64 KB
    const size_t wptBytes = (size_t)512 * 1024 * sizeof(float2);   // 4 MB / image
    const size_t pBytes   = (size_t)1024 * 1024 * sizeof(float);   // 4 MB / image
    size_t avail = (ws_size > 65536) ? (ws_size - 65536) : 0;
    int chunk = (int)(avail / (wptBytes + pBytes));
    if (chunk > NIMG) chunk = NIMG;
    if (chunk < 1) chunk = 1;

    float2* WpT = (float2*)(ws + 65536);
    float*  P   = (float*)(ws + 65536 + (size_t)chunk * wptBytes);

    for (int base = 0; base < NIMG; base += chunk) {
        int c = (NIMG - base < chunk) ? (NIMG - base) : chunk;
        fft_rows<<<dim3(64, c), 512, 0, stream>>>(outp, tgtp, WpT, base);
        fft_cols_store<<<dim3(129, c), 512, 0, stream>>>(WpT, P, base);
        bin_rings<<<dim3(RADIUS, c), 256, 0, stream>>>(P, rad, base);
    }

    final_loss<<<1, 256, 0, stream>>>(rad, dout);
}

// Round 10
// 191.241 us; speedup vs baseline: 1.4708x; 1.4708x over previous
//
#include <hip/hip_runtime.h>
#include <math.h>

#define S 1024
#define RADIUS 512
#define NIMG 32   // 16 "output" images then 16 "target" images
#define RGROUP 16 // rows per bin_scan block

// ---------------------------------------------------------------------------
// Complex helpers
// ---------------------------------------------------------------------------
__device__ __forceinline__ float2 cmul(float2 a, float2 b) {
    return make_float2(a.x * b.x - a.y * b.y, a.x * b.y + a.y * b.x);
}
__device__ __forceinline__ float2 cadd(float2 a, float2 b) { return make_float2(a.x + b.x, a.y + b.y); }
__device__ __forceinline__ float2 csub(float2 a, float2 b) { return make_float2(a.x - b.x, a.y - b.y); }

// W_16^k, k=0..7
__device__ const float2 C16[8] = {
    {1.0f, 0.0f},
    {0.92387953251128674f, -0.38268343236508978f},
    {0.70710678118654757f, -0.70710678118654746f},
    {0.38268343236508984f, -0.92387953251128674f},
    {0.0f, -1.0f},
    {-0.38268343236508973f, -0.92387953251128674f},
    {-0.70710678118654746f, -0.70710678118654757f},
    {-0.92387953251128663f, -0.38268343236508989f},
};
// W_8^k, k=0..3
__device__ const float2 C8T[4] = {
    {1.0f, 0.0f},
    {0.70710678118654757f, -0.70710678118654746f},
    {0.0f, -1.0f},
    {-0.70710678118654746f, -0.70710678118654757f},
};
// W512^m, m=0..7
__device__ const float2 W512T[8] = {
    {1.0f, 0.0f},
    {0.99992470183914454f, -0.012271538285719925f},
    {0.99969881869620425f, -0.024541228522912288f},
    {0.99932238458834954f, -0.036807222941358832f},
    {0.99879545620517241f, -0.049067674327418015f},
    {0.99811811290014918f, -0.061320736302208578f},
    {0.99729045667869021f, -0.073564563599667426f},
    {0.99631261218277800f, -0.085797312344439894f},
};
// W64^k, k=0..7
__device__ const float2 W64T[8] = {
    {1.0f, 0.0f},
    {0.99518472667219693f, -0.098017140329560604f},
    {0.98078528040323044f, -0.19509032201612825f},
    {0.95694033573220886f, -0.29028467725446233f},
    {0.92387953251128674f, -0.38268343236508978f},
    {0.88192126434835505f, -0.47139673682599764f},
    {0.83146961230254524f, -0.55557023301960218f},
    {0.77301045336273699f, -0.63439328416364549f},
};
// W128^h (plain order), h=0..7
__device__ const float2 W128P[8] = {
    {1.0f, 0.0f},
    {0.99879545620517241f, -0.049067674327418015f},
    {0.99518472667219693f, -0.098017140329560604f},
    {0.98917650996478101f, -0.14673047445536175f},
    {0.98078528040323044f, -0.19509032201612825f},
    {0.97003125319454397f, -0.24298017990326390f},
    {0.95694033573220886f, -0.29028467725446233f},
    {0.94154406518302081f, -0.33688985339222005f},
};
// W1024^l (plain order), l=0..7
__device__ const float2 W1024P[8] = {
    {1.0f, 0.0f},
    {0.99998117528260111f, -0.0061358846491544753f},
    {0.99992470183914454f, -0.012271538285719925f},
    {0.99983058179582340f, -0.018406729905804820f},
    {0.99969881869620425f, -0.024541228522912288f},
    {0.99952941750109314f, -0.030674803176636626f},
    {0.99932238458834954f, -0.036807222941358832f},
    {0.99907772775264536f, -0.042938256934940820f},
};

// 4 radix-2 DIF stages over 16 register elements (pass A)
__device__ __forceinline__ void fft16(float2 r[16], float2 T) {
    float2 tc[8];
    #pragma unroll
    for (int u = 0; u < 8; ++u) tc[u] = cmul(T, C16[u]);
    #pragma unroll
    for (int u = 0; u < 8; ++u) {
        float2 a = r[u], b = r[u + 8];
        r[u] = cadd(a, b);
        r[u + 8] = cmul(csub(a, b), tc[u]);
    }
    T = cmul(T, T);
    #pragma unroll
    for (int u = 0; u < 4; ++u) tc[u] = cmul(T, C16[2 * u]);
    #pragma unroll
    for (int g = 0; g < 2; ++g)
        #pragma unroll
        for (int u = 0; u < 4; ++u) {
            int lo = g * 8 + u;
            float2 a = r[lo], b = r[lo + 4];
            r[lo] = cadd(a, b);
            r[lo + 4] = cmul(csub(a, b), tc[u]);
        }
    T = cmul(T, T);
    #pragma unroll
    for (int u = 0; u < 2; ++u) tc[u] = cmul(T, C16[4 * u]);
    #pragma unroll
    for (int g = 0; g < 4; ++g)
        #pragma unroll
        for (int u = 0; u < 2; ++u) {
            int lo = g * 4 + u;
            float2 a = r[lo], b = r[lo + 2];
            r[lo] = cadd(a, b);
            r[lo + 2] = cmul(csub(a, b), tc[u]);
        }
    T = cmul(T, T);
    #pragma unroll
    for (int g = 0; g < 8; ++g) {
        int lo = g * 2;
        float2 a = r[lo], b = r[lo + 1];
        r[lo] = cadd(a, b);
        r[lo + 1] = cmul(csub(a, b), T);
    }
}

// 3 radix-2 DIF stages over 8 register elements
__device__ __forceinline__ void fft8(float2 r[8], float2 T) {
    float2 tc[4];
    #pragma unroll
    for (int u = 0; u < 4; ++u) tc[u] = cmul(T, C8T[u]);
    #pragma unroll
    for (int u = 0; u < 4; ++u) {
        float2 a = r[u], b = r[u + 4];
        r[u] = cadd(a, b);
        r[u + 4] = cmul(csub(a, b), tc[u]);
    }
    T = cmul(T, T);
    #pragma unroll
    for (int u = 0; u < 2; ++u) tc[u] = cmul(T, C8T[2 * u]);
    #pragma unroll
    for (int g = 0; g < 2; ++g)
        #pragma unroll
        for (int u = 0; u < 2; ++u) {
            int lo = g * 4 + u;
            float2 a = r[lo], b = r[lo + 2];
            r[lo] = cadd(a, b);
            r[lo + 2] = cmul(csub(a, b), tc[u]);
        }
    T = cmul(T, T);
    #pragma unroll
    for (int g = 0; g < 4; ++g) {
        int lo = g * 2;
        float2 a = r[lo], b = r[lo + 1];
        r[lo] = cadd(a, b);
        r[lo + 1] = cmul(csub(a, b), T);
    }
}

// Last 2 DIF stages (1024-pt, pass A): quad-perm shuffles across c = tau&3
__device__ __forceinline__ void fft_last2(float2 r[16], int c) {
    #pragma unroll
    for (int m = 0; m < 16; ++m) {
        float vx = __shfl_xor(r[m].x, 2, 64);
        float vy = __shfl_xor(r[m].y, 2, 64);
        if (c & 2) {
            float dx = vx - r[m].x, dy = vy - r[m].y;
            if (c & 1) { r[m].x = dy; r[m].y = -dx; }
            else       { r[m].x = dx; r[m].y = dy; }
        } else {
            r[m].x += vx; r[m].y += vy;
        }
    }
    #pragma unroll
    for (int m = 0; m < 16; ++m) {
        float vx = __shfl_xor(r[m].x, 1, 64);
        float vy = __shfl_xor(r[m].y, 1, 64);
        if (c & 1) { r[m].x = vx - r[m].x; r[m].y = vy - r[m].y; }
        else       { r[m].x += vx; r[m].y += vy; }
    }
}

// Swizzled LDS addr for 1024-pt transpose (pass A)
__device__ __forceinline__ int A1x(int n) {
    int j = n >> 6;
    return (n & ~63) | ((n & 63) ^ (j << 2));
}

__device__ __forceinline__ int bitrev3(int x) {
    return ((x & 1) << 2) | (x & 2) | ((x >> 2) & 1);
}

// ---------------------------------------------------------------------------
// Pass A: packed row-pair FFTs (unchanged — validated).
// ---------------------------------------------------------------------------
__global__ __launch_bounds__(512)
void fft_rows(const float* __restrict__ outp, const float* __restrict__ tgtp,
              float2* __restrict__ WpT, int imgBase) {
    __shared__ float2 buf[8 * 1024];
    const int t = threadIdx.x;
    const int w = t >> 6, tau = t & 63;
    const int yy = blockIdx.x * 8 + w;
    const int i = blockIdx.y, g = imgBase + i;
    const float* img = (g < 16 ? outp : tgtp) + (size_t)(g & 15) * S * S;
    const float* r0 = img + (size_t)(2 * yy) * S;
    const float* r1 = r0 + S;

    float2 r[16];
    #pragma unroll
    for (int j = 0; j < 16; ++j) r[j] = make_float2(r0[64 * j + tau], r1[64 * j + tau]);

    float2 T;
    { float sv, cv; sincosf(-6.283185307179586f * (float)tau / 1024.0f, &sv, &cv); T = make_float2(cv, sv); }
    fft16(r, T);

    float2* mybuf = buf + (w << 10);
    #pragma unroll
    for (int j = 0; j < 16; ++j) mybuf[A1x(64 * j + tau)] = r[j];
    const int b = tau >> 2, c = tau & 3;
    #pragma unroll
    for (int m = 0; m < 16; ++m) r[m] = mybuf[(b << 6) + 4 * (m ^ b) + c];

    { float sv, cv; sincosf(-6.283185307179586f * (float)c / 64.0f, &sv, &cv); T = make_float2(cv, sv); }
    fft16(r, T);
    fft_last2(r, c);

    #pragma unroll
    for (int m = 0; m < 16; ++m) {
        int n = (b << 6) + 4 * m + c;
        int k = (int)(__brev((unsigned)n) >> 22);
        mybuf[k ^ (w << 1)] = r[m];
    }
    __syncthreads();

    const int yy0 = blockIdx.x * 8;
    float2* dst = WpT + (size_t)i * 512 * 1024;
    #pragma unroll
    for (int q = 0; q < 16; ++q) {
        int idx = q * 512 + t;
        int uu = idx >> 3, wv = idx & 7;
        float2 val = buf[(wv << 10) | (uu ^ (wv << 1))];
        dst[(size_t)uu * 512 + yy0 + wv] = val;
    }
}

// ---------------------------------------------------------------------------
// Pass B1: split-wave FFT + combine + |G|^2 store (unchanged — validated R9).
// ---------------------------------------------------------------------------
__global__ __launch_bounds__(512, 4)
void fft_cols_store(const float2* __restrict__ WpT, float* __restrict__ P, int imgBase) {
    __shared__ float2 tbuf[8 * 512];          // 32 KB: 512-slot buffer per wave
    const int t = threadIdx.x;
    const int w = t >> 6, tau = t & 63;
    const int i = blockIdx.y;
    const int u = blockIdx.x * 4 + (w >> 1);  // 4 u-values per block
    const int setb = w & 1;                   // 0: X0 FFT, 1: X1 FFT
    const bool active = (u <= 512);

    const int b3 = tau >> 3, lam = tau & 7;
    float2 X[8];
    float2* mb = tbuf + (w << 9);

    if (active) {
        const float2* Wimg = WpT + (size_t)i * 512 * 1024;
        const int mu = (1024 - u) & 1023;
        const float2* rowA = Wimg + (size_t)u * 512;
        const float2* rowM = Wimg + (size_t)mu * 512;

        #pragma unroll
        for (int j = 0; j < 8; ++j) {
            float2 A = rowA[64 * j + tau];
            float2 M = rowM[64 * j + tau];
            X[j] = (setb == 0)
                 ? make_float2(0.5f * (A.x + M.x), 0.5f * (A.y - M.y))
                 : make_float2(0.5f * (A.y + M.y), 0.5f * (M.x - A.x));
        }

        // Phase 1; T = W512^tau = W64^{b3} * W512^{lam}
        fft8(X, cmul(W64T[b3], W512T[lam]));

        // Transpose 1 (wave-private, swizzled, conflict-free)
        #pragma unroll
        for (int j = 0; j < 8; ++j) mb[(j << 6) | (tau ^ (j << 3) ^ j)] = X[j];
        #pragma unroll
        for (int c = 0; c < 8; ++c) X[c] = mb[(b3 << 6) | (((c ^ b3) << 3) | (lam ^ b3))];

        // Phase 2; T = W64^{lam}
        fft8(X, W64T[lam]);

        // Transpose 2
        #pragma unroll
        for (int c = 0; c < 8; ++c) mb[(b3 << 6) | (((c ^ b3) << 3) | (lam ^ b3))] = X[c];
        #pragma unroll
        for (int d = 0; d < 8; ++d) X[d] = mb[(b3 << 6) | (((lam ^ b3) << 3) | (d ^ b3))];

        // Phase 3 (T = 1)
        fft8(X, make_float2(1.0f, 0.0f));

        // Publish in NATURAL-f order: X[d] is freq f = 64*rev3(d) + 8*rev3(lam) + rev3(b3).
        const int base9 = 8 * bitrev3(lam) + bitrev3(b3);
        #pragma unroll
        for (int d = 0; d < 8; ++d) {
            mb[(bitrev3(d) << 6) + base9] = X[d];
        }
    }
    __syncthreads();   // cross-wave exchange (all threads reach this)

    if (active) {
        const float2* b0 = tbuf + ((w & ~1) << 9);   // X0-hat, natural-f
        const float2* b1 = tbuf + ((w | 1) << 9);    // X1-hat, natural-f
        const float2 Wtau = cmul(W128P[tau >> 3], W1024P[tau & 7]);  // W1024^tau
        float* Pimg = P + (size_t)i * 1024 * 1024;
        const int um = (1024 - u) & 1023;

        #pragma unroll
        for (int m = 0; m < 8; ++m) {
            const int f = tau + 64 * m;
            float2 x0 = b0[f];
            float2 x1 = b1[f];
            float2 Wf = cmul(Wtau, C16[m]);          // W1024^f
            float2 wx = cmul(Wf, x1);
            float2 G = (setb == 0) ? cadd(x0, wx)    // v = f
                                   : csub(x0, wx);   // v = f + 512
            float p = G.x * G.x + G.y * G.y;
            const int v = f + (setb << 9);
            Pimg[(size_t)u * 1024 + v] = p;
            const int vm = (1024 - v) & 1023;        // conjugate mirror
            Pimg[(size_t)um * 1024 + vm] = p;        // idempotent at u=0,512
        }
    }
}

// ---------------------------------------------------------------------------
// Pass B2 (ROUND 10): scan-based ring binning. Block = (16 u-rows, image).
// Per row: coalesced load (every pixel read exactly once), fold to 512,
// wave-shuffle inclusive scan + 8-wave offset combine, then thread r (ring r)
// takes its window sum as a prefix difference:
//   ring r window in folded v: [vlo, vhi), vlo/vhi = ceil(sqrt(r^2-cu^2)-0.5)
// (boundary math identical to validated R9 bin_rings — exact quarter-integer
// arguments, no ties). Zero atomics, zero over-fetch.
// ---------------------------------------------------------------------------
__global__ __launch_bounds__(512)
void bin_scan(const float* __restrict__ P, float* __restrict__ partial, int imgBase) {
    __shared__ float pref[512];
    __shared__ float cws[8];    // per-wave totals
    __shared__ float cwx[8];    // exclusive cumulative wave sums
    const int t = threadIdx.x;
    const int lane = t & 63, w = t >> 6;
    const int i = blockIdx.y;
    const int g = imgBase + i;
    const int u0 = blockIdx.x * RGROUP;
    const float* Pimg = P + (size_t)i * 1024 * 1024;

    const int r = t;                       // thread t owns ring t
    const float r2  = (float)(r * r);
    const float r12 = (float)((r + 1) * (r + 1));
    float acc = 0.0f;

    for (int k = 0; k < RGROUP; ++k) {
        const int u = u0 + k;
        const float* row = Pimg + (size_t)u * 1024;
        float F = row[t] + row[1023 - t];  // fold: |cv| = t + 0.5

        // wave-level inclusive scan (6 shuffle steps)
        float s = F;
        #pragma unroll
        for (int off = 1; off < 64; off <<= 1) {
            float n = __shfl_up(s, off, 64);
            if (lane >= off) s += n;
        }
        pref[t] = s;
        if (lane == 63) cws[w] = s;        // wave total
        __syncthreads();
        if (t < 8) {
            float x = 0.0f;
            #pragma unroll
            for (int j = 0; j < 8; ++j) {
                if (j < t) x += cws[j];
            }
            cwx[t] = x;
        }
        __syncthreads();

        const float cu = (u < 512) ? (u + 0.5f) : (u - 1023.5f);
        const float cu2 = cu * cu;         // exact in f32
        const float Bv = r12 - cu2;        // exact
        if (Bv > 0.0f) {
            const float Av = r2 - cu2;     // exact
            float cvlo = (Av > 0.0f) ? sqrtf(Av) : 0.0f;
            float cvhi = sqrtf(Bv);
            int vlo = (int)ceilf(cvlo - 0.5f);   // first vv with vv+0.5 >= cvlo
            int vhi = (int)ceilf(cvhi - 0.5f);
            if (vhi > 512) vhi = 512;
            if (vlo < 0) vlo = 0;
            if (vhi > vlo) {
                float hi = pref[vhi - 1] + cwx[(vhi - 1) >> 6];
                float lo = (vlo > 0) ? (pref[vlo - 1] + cwx[(vlo - 1) >> 6]) : 0.0f;
                acc += hi - lo;
            }
        }
        __syncthreads();                   // before pref overwrite next row
    }
    // partial[g][blockIdx.x][r]; every slot written every call
    partial[(((size_t)g * 64) + blockIdx.x) * 512 + t] = acc;
}

// ---------------------------------------------------------------------------
// Fold partials -> rad  (coalesced: block per image, 64 row-group partials)
// ---------------------------------------------------------------------------
__global__ __launch_bounds__(512)
void reduce_partials(const float* __restrict__ partial, float* __restrict__ rad) {
    const int g = blockIdx.x;
    const int t = threadIdx.x;
    const float* p = partial + (size_t)g * 64 * 512;
    float s = 0.0f;
    for (int b = 0; b < 64; ++b) s += p[(size_t)b * 512 + t];
    rad[(size_t)g * 512 + t] = s;
}

// ---------------------------------------------------------------------------
// Final: loss = mean(|rad_out - rad_tgt|) / S^2
// ---------------------------------------------------------------------------
__global__ __launch_bounds__(256)
void final_loss(const float* __restrict__ rad, float* __restrict__ out) {
    __shared__ float red[256];
    const int t = threadIdx.x;
    float acc = 0.0f;
    for (int i = t; i < 16 * RADIUS; i += 256) {
        int bb = i >> 9;
        int rr = i & (RADIUS - 1);
        float o = rad[(size_t)bb * RADIUS + rr];
        float gg = rad[(size_t)(bb + 16) * RADIUS + rr];
        acc += fabsf(o - gg);
    }
    red[t] = acc;
    __syncthreads();
    for (int off = 128; off > 0; off >>= 1) {
        if (t < off) red[t] += red[t + off];
        __syncthreads();
    }
    if (t == 0) {
        out[0] = red[0] / ((float)S * (float)S) / (16.0f * (float)RADIUS);
    }
}

extern "C" void kernel_launch(void* const* d_in, const int* in_sizes, int n_in,
                              void* d_out, int out_size, void* d_ws, size_t ws_size,
                              hipStream_t stream) {
    const float* outp = (const float*)d_in[0];
    const float* tgtp = (const float*)d_in[1];
    float* dout = (float*)d_out;

    char* ws = (char*)d_ws;
    float* rad = (float*)ws;                                  // 64 KB
    const size_t partBytes = (size_t)NIMG * 64 * 512 * sizeof(float);  // 4 MB
    float* partial = (float*)(ws + 65536);
    const size_t wptBytes = (size_t)512 * 1024 * sizeof(float2);   // 4 MB / image
    const size_t pBytes   = (size_t)1024 * 1024 * sizeof(float);   // 4 MB / image
    size_t used = 65536 + partBytes;
    size_t avail = (ws_size > used) ? (ws_size - used) : 0;
    int chunk = (int)(avail / (wptBytes + pBytes));
    if (chunk > NIMG) chunk = NIMG;
    if (chunk < 1) chunk = 1;

    float2* WpT = (float2*)(ws + used);
    float*  P   = (float*)(ws + used + (size_t)chunk * wptBytes);

    for (int base = 0; base < NIMG; base += chunk) {
        int c = (NIMG - base < chunk) ? (NIMG - base) : chunk;
        fft_rows<<<dim3(64, c), 512, 0, stream>>>(outp, tgtp, WpT, base);
        fft_cols_store<<<dim3(129, c), 512, 0, stream>>>(WpT, P, base);
        bin_scan<<<dim3(64, c), 512, 0, stream>>>(P, partial, base);
    }

    reduce_partials<<<NIMG, 512, 0, stream>>>(partial, rad);
    final_loss<<<1, 256, 0, stream>>>(rad, dout);
}

// Round 11
// 171.499 us; speedup vs baseline: 1.6401x; 1.1151x over previous
//
#include <hip/hip_runtime.h>
#include <math.h>

#define S 1024
#define RADIUS 512
#define NIMG 32   // 16 "output" images then 16 "target" images
#define PBX 129   // pass-B blocks per image (u-groups of 4)

// ---------------------------------------------------------------------------
// Complex helpers
// ---------------------------------------------------------------------------
__device__ __forceinline__ float2 cmul(float2 a, float2 b) {
    return make_float2(a.x * b.x - a.y * b.y, a.x * b.y + a.y * b.x);
}
__device__ __forceinline__ float2 cadd(float2 a, float2 b) { return make_float2(a.x + b.x, a.y + b.y); }
__device__ __forceinline__ float2 csub(float2 a, float2 b) { return make_float2(a.x - b.x, a.y - b.y); }

// W_16^k, k=0..7
__device__ const float2 C16[8] = {
    {1.0f, 0.0f},
    {0.92387953251128674f, -0.38268343236508978f},
    {0.70710678118654757f, -0.70710678118654746f},
    {0.38268343236508984f, -0.92387953251128674f},
    {0.0f, -1.0f},
    {-0.38268343236508973f, -0.92387953251128674f},
    {-0.70710678118654746f, -0.70710678118654757f},
    {-0.92387953251128663f, -0.38268343236508989f},
};
// W_8^k, k=0..3
__device__ const float2 C8T[4] = {
    {1.0f, 0.0f},
    {0.70710678118654757f, -0.70710678118654746f},
    {0.0f, -1.0f},
    {-0.70710678118654746f, -0.70710678118654757f},
};
// W512^m, m=0..7
__device__ const float2 W512T[8] = {
    {1.0f, 0.0f},
    {0.99992470183914454f, -0.012271538285719925f},
    {0.99969881869620425f, -0.024541228522912288f},
    {0.99932238458834954f, -0.036807222941358832f},
    {0.99879545620517241f, -0.049067674327418015f},
    {0.99811811290014918f, -0.061320736302208578f},
    {0.99729045667869021f, -0.073564563599667426f},
    {0.99631261218277800f, -0.085797312344439894f},
};
// W64^k, k=0..7
__device__ const float2 W64T[8] = {
    {1.0f, 0.0f},
    {0.99518472667219693f, -0.098017140329560604f},
    {0.98078528040323044f, -0.19509032201612825f},
    {0.95694033573220886f, -0.29028467725446233f},
    {0.92387953251128674f, -0.38268343236508978f},
    {0.88192126434835505f, -0.47139673682599764f},
    {0.83146961230254524f, -0.55557023301960218f},
    {0.77301045336273699f, -0.63439328416364549f},
};
// W128^h (plain order), h=0..7
__device__ const float2 W128P[8] = {
    {1.0f, 0.0f},
    {0.99879545620517241f, -0.049067674327418015f},
    {0.99518472667219693f, -0.098017140329560604f},
    {0.98917650996478101f, -0.14673047445536175f},
    {0.98078528040323044f, -0.19509032201612825f},
    {0.97003125319454397f, -0.24298017990326390f},
    {0.95694033573220886f, -0.29028467725446233f},
    {0.94154406518302081f, -0.33688985339222005f},
};
// W1024^l (plain order), l=0..7
__device__ const float2 W1024P[8] = {
    {1.0f, 0.0f},
    {0.99998117528260111f, -0.0061358846491544753f},
    {0.99992470183914454f, -0.012271538285719925f},
    {0.99983058179582340f, -0.018406729905804820f},
    {0.99969881869620425f, -0.024541228522912288f},
    {0.99952941750109314f, -0.030674803176636626f},
    {0.99932238458834954f, -0.036807222941358832f},
    {0.99907772775264536f, -0.042938256934940820f},
};

// 4 radix-2 DIF stages over 16 register elements (pass A)
__device__ __forceinline__ void fft16(float2 r[16], float2 T) {
    float2 tc[8];
    #pragma unroll
    for (int u = 0; u < 8; ++u) tc[u] = cmul(T, C16[u]);
    #pragma unroll
    for (int u = 0; u < 8; ++u) {
        float2 a = r[u], b = r[u + 8];
        r[u] = cadd(a, b);
        r[u + 8] = cmul(csub(a, b), tc[u]);
    }
    T = cmul(T, T);
    #pragma unroll
    for (int u = 0; u < 4; ++u) tc[u] = cmul(T, C16[2 * u]);
    #pragma unroll
    for (int g = 0; g < 2; ++g)
        #pragma unroll
        for (int u = 0; u < 4; ++u) {
            int lo = g * 8 + u;
            float2 a = r[lo], b = r[lo + 4];
            r[lo] = cadd(a, b);
            r[lo + 4] = cmul(csub(a, b), tc[u]);
        }
    T = cmul(T, T);
    #pragma unroll
    for (int u = 0; u < 2; ++u) tc[u] = cmul(T, C16[4 * u]);
    #pragma unroll
    for (int g = 0; g < 4; ++g)
        #pragma unroll
        for (int u = 0; u < 2; ++u) {
            int lo = g * 4 + u;
            float2 a = r[lo], b = r[lo + 2];
            r[lo] = cadd(a, b);
            r[lo + 2] = cmul(csub(a, b), tc[u]);
        }
    T = cmul(T, T);
    #pragma unroll
    for (int g = 0; g < 8; ++g) {
        int lo = g * 2;
        float2 a = r[lo], b = r[lo + 1];
        r[lo] = cadd(a, b);
        r[lo + 1] = cmul(csub(a, b), T);
    }
}

// 3 radix-2 DIF stages over 8 register elements
__device__ __forceinline__ void fft8(float2 r[8], float2 T) {
    float2 tc[4];
    #pragma unroll
    for (int u = 0; u < 4; ++u) tc[u] = cmul(T, C8T[u]);
    #pragma unroll
    for (int u = 0; u < 4; ++u) {
        float2 a = r[u], b = r[u + 4];
        r[u] = cadd(a, b);
        r[u + 4] = cmul(csub(a, b), tc[u]);
    }
    T = cmul(T, T);
    #pragma unroll
    for (int u = 0; u < 2; ++u) tc[u] = cmul(T, C8T[2 * u]);
    #pragma unroll
    for (int g = 0; g < 2; ++g)
        #pragma unroll
        for (int u = 0; u < 2; ++u) {
            int lo = g * 4 + u;
            float2 a = r[lo], b = r[lo + 2];
            r[lo] = cadd(a, b);
            r[lo + 2] = cmul(csub(a, b), tc[u]);
        }
    T = cmul(T, T);
    #pragma unroll
    for (int g = 0; g < 4; ++g) {
        int lo = g * 2;
        float2 a = r[lo], b = r[lo + 1];
        r[lo] = cadd(a, b);
        r[lo + 1] = cmul(csub(a, b), T);
    }
}

// Last 2 DIF stages (1024-pt, pass A): quad-perm shuffles across c = tau&3
__device__ __forceinline__ void fft_last2(float2 r[16], int c) {
    #pragma unroll
    for (int m = 0; m < 16; ++m) {
        float vx = __shfl_xor(r[m].x, 2, 64);
        float vy = __shfl_xor(r[m].y, 2, 64);
        if (c & 2) {
            float dx = vx - r[m].x, dy = vy - r[m].y;
            if (c & 1) { r[m].x = dy; r[m].y = -dx; }
            else       { r[m].x = dx; r[m].y = dy; }
        } else {
            r[m].x += vx; r[m].y += vy;
        }
    }
    #pragma unroll
    for (int m = 0; m < 16; ++m) {
        float vx = __shfl_xor(r[m].x, 1, 64);
        float vy = __shfl_xor(r[m].y, 1, 64);
        if (c & 1) { r[m].x = vx - r[m].x; r[m].y = vy - r[m].y; }
        else       { r[m].x += vx; r[m].y += vy; }
    }
}

// Swizzled LDS addr for 1024-pt transpose (pass A)
__device__ __forceinline__ int A1x(int n) {
    int j = n >> 6;
    return (n & ~63) | ((n & 63) ^ (j << 2));
}

__device__ __forceinline__ int bitrev3(int x) {
    return ((x & 1) << 2) | (x & 2) | ((x >> 2) & 1);
}

// ---------------------------------------------------------------------------
// Pass A: packed row-pair FFTs. R11 change: sincosf -> twiddle-table products
// (W1024^tau = W128P[tau>>3]*W1024P[tau&7]; W64^c from W64T). Rest validated.
// ---------------------------------------------------------------------------
__global__ __launch_bounds__(512)
void fft_rows(const float* __restrict__ outp, const float* __restrict__ tgtp,
              float2* __restrict__ WpT, int imgBase) {
    __shared__ float2 buf[8 * 1024];
    const int t = threadIdx.x;
    const int w = t >> 6, tau = t & 63;
    const int yy = blockIdx.x * 8 + w;
    const int i = blockIdx.y, g = imgBase + i;
    const float* img = (g < 16 ? outp : tgtp) + (size_t)(g & 15) * S * S;
    const float* r0 = img + (size_t)(2 * yy) * S;
    const float* r1 = r0 + S;

    float2 r[16];
    #pragma unroll
    for (int j = 0; j < 16; ++j) r[j] = make_float2(r0[64 * j + tau], r1[64 * j + tau]);

    // T = W1024^tau (table product, no sincosf)
    float2 T = cmul(W128P[tau >> 3], W1024P[tau & 7]);
    fft16(r, T);

    float2* mybuf = buf + (w << 10);
    #pragma unroll
    for (int j = 0; j < 16; ++j) mybuf[A1x(64 * j + tau)] = r[j];
    const int b = tau >> 2, c = tau & 3;
    #pragma unroll
    for (int m = 0; m < 16; ++m) r[m] = mybuf[(b << 6) + 4 * (m ^ b) + c];

    fft16(r, W64T[c]);          // T = W64^c
    fft_last2(r, c);

    #pragma unroll
    for (int m = 0; m < 16; ++m) {
        int n = (b << 6) + 4 * m + c;
        int k = (int)(__brev((unsigned)n) >> 22);
        mybuf[k ^ (w << 1)] = r[m];
    }
    __syncthreads();

    const int yy0 = blockIdx.x * 8;
    float2* dst = WpT + (size_t)i * 512 * 1024;
    #pragma unroll
    for (int q = 0; q < 16; ++q) {
        int idx = q * 512 + t;
        int uu = idx >> 3, wv = idx & 7;
        float2 val = buf[(wv << 10) | (uu ^ (wv << 1))];
        dst[(size_t)uu * 512 + yy0 + wv] = val;
    }
}

// ---------------------------------------------------------------------------
// Pass B (ROUND 11, fused): split-wave FFT + combine (validated R9/R10) +
// in-block scan binning (validated R10) — NO P image, NO extra HBM round-trip.
// After combine, the wave pair for column u holds its full 1024-power row in
// registers -> LDS (aliasing tbuf after spectra reads complete). Then for each
// of the 4 direct rows AND 4 conjugate-mirror rows (mirror = permutation of
// the direct row: F_um[t] = PR[t+1] + PR[(1024-t)&1023], |cu| = u-0.5):
// fold -> wave shuffle scan -> ring window prefix-difference (exact
// quarter-integer boundary math). Thread t owns ring t across all rows.
// Zero atomics. Per-block output: one 512-float partial.
// ---------------------------------------------------------------------------
__global__ __launch_bounds__(512, 4)
void fft_cols_bin2(const float2* __restrict__ WpT, float* __restrict__ partial, int imgBase) {
    __shared__ float2 tbuf[8 * 512];      // 32 KB spectra; aliased as Prow[4][1024] floats
    __shared__ float pref[512];
    __shared__ float cws[8];
    __shared__ float cwx[8];
    const int t = threadIdx.x;
    const int w = t >> 6, tau = t & 63;
    const int i = blockIdx.y, g = imgBase + i;
    const int l = w >> 1;                 // local u index 0..3
    const int u = blockIdx.x * 4 + l;     // 0..515
    const int setb = w & 1;               // 0: X0 FFT (v=f), 1: X1 FFT (v=f+512)
    const bool active = (u <= 512);

    const int b3 = tau >> 3, lam = tau & 7;
    float2 X[8];
    float2* mb = tbuf + (w << 9);

    if (active) {
        const float2* Wimg = WpT + (size_t)i * 512 * 1024;
        const int mu = (1024 - u) & 1023;
        const float2* rowA = Wimg + (size_t)u * 512;
        const float2* rowM = Wimg + (size_t)mu * 512;

        #pragma unroll
        for (int j = 0; j < 8; ++j) {
            float2 A = rowA[64 * j + tau];
            float2 M = rowM[64 * j + tau];
            X[j] = (setb == 0)
                 ? make_float2(0.5f * (A.x + M.x), 0.5f * (A.y - M.y))
                 : make_float2(0.5f * (A.y + M.y), 0.5f * (M.x - A.x));
        }

        // Phase 1; T = W512^tau = W64^{b3} * W512^{lam}
        fft8(X, cmul(W64T[b3], W512T[lam]));

        // Transpose 1 (wave-private, swizzled, conflict-free)
        #pragma unroll
        for (int j = 0; j < 8; ++j) mb[(j << 6) | (tau ^ (j << 3) ^ j)] = X[j];
        #pragma unroll
        for (int c = 0; c < 8; ++c) X[c] = mb[(b3 << 6) | (((c ^ b3) << 3) | (lam ^ b3))];

        // Phase 2; T = W64^{lam}
        fft8(X, W64T[lam]);

        // Transpose 2
        #pragma unroll
        for (int c = 0; c < 8; ++c) mb[(b3 << 6) | (((c ^ b3) << 3) | (lam ^ b3))] = X[c];
        #pragma unroll
        for (int d = 0; d < 8; ++d) X[d] = mb[(b3 << 6) | (((lam ^ b3) << 3) | (d ^ b3))];

        // Phase 3 (T = 1)
        fft8(X, make_float2(1.0f, 0.0f));

        // Publish in NATURAL-f order: X[d] is freq f = 64*rev3(d)+8*rev3(lam)+rev3(b3)
        const int base9 = 8 * bitrev3(lam) + bitrev3(b3);
        #pragma unroll
        for (int d = 0; d < 8; ++d) {
            mb[(bitrev3(d) << 6) + base9] = X[d];
        }
    }
    __syncthreads();   // cross-wave spectra exchange

    float p[8];
    if (active) {
        const float2* b0 = tbuf + ((w & ~1) << 9);   // X0-hat, natural-f
        const float2* b1 = tbuf + ((w | 1) << 9);    // X1-hat, natural-f
        const float2 Wtau = cmul(W128P[tau >> 3], W1024P[tau & 7]);  // W1024^tau
        #pragma unroll
        for (int m = 0; m < 8; ++m) {
            const int f = tau + 64 * m;
            float2 x0 = b0[f];
            float2 x1 = b1[f];
            float2 Wf = cmul(Wtau, C16[m]);          // W1024^f
            float2 wx = cmul(Wf, x1);
            float2 G = (setb == 0) ? cadd(x0, wx)    // v = f
                                   : csub(x0, wx);   // v = f + 512
            p[m] = G.x * G.x + G.y * G.y;
        }
    }
    __syncthreads();   // all spectra reads done -> safe to alias Prow onto tbuf

    float* Prow = (float*)tbuf;                      // [4][1024]
    if (active) {
        #pragma unroll
        for (int m = 0; m < 8; ++m) {
            const int v = tau + 64 * m + (setb << 9);
            Prow[(l << 10) + v] = p[m];              // 64 consecutive floats/wave-instr
        }
    }
    __syncthreads();

    // ---- in-block scan binning: thread t owns ring t ----
    const int r = t;
    const float r2  = (float)(r * r);
    const float r12 = (float)((r + 1) * (r + 1));
    float acc = 0.0f;

    for (int rowi = 0; rowi < 8; ++rowi) {
        const int ll = rowi >> 1;
        const int mir = rowi & 1;
        const int uu = blockIdx.x * 4 + ll;
        const bool valid = (uu <= 512) && (!mir || (uu >= 1 && uu <= 511));
        float F = 0.0f;
        if (valid) {
            const float* PR = Prow + (ll << 10);
            F = mir ? (PR[t + 1] + PR[(1024 - t) & 1023])   // mirror row (permutation)
                    : (PR[t] + PR[1023 - t]);               // direct row fold
        }
        // wave-level inclusive scan (6 shuffle steps)
        float s = F;
        #pragma unroll
        for (int off = 1; off < 64; off <<= 1) {
            float n = __shfl_up(s, off, 64);
            if (tau >= off) s += n;
        }
        pref[t] = s;
        if (tau == 63) cws[w] = s;
        __syncthreads();
        if (t < 8) {
            float x = 0.0f;
            #pragma unroll
            for (int j = 0; j < 8; ++j) {
                if (j < t) x += cws[j];
            }
            cwx[t] = x;
        }
        __syncthreads();
        if (valid) {
            // |column coordinate|: direct u<512: u+0.5; u=512: 511.5; mirror: u-0.5
            const float cuv = mir ? ((float)uu - 0.5f)
                                  : ((uu < 512) ? ((float)uu + 0.5f) : 511.5f);
            const float cu2 = cuv * cuv;      // exact in f32 (quarter-integer < 2^19)
            const float Bv = r12 - cu2;       // exact
            if (Bv > 0.0f) {
                const float Av = r2 - cu2;    // exact
                float cvlo = (Av > 0.0f) ? sqrtf(Av) : 0.0f;
                float cvhi = sqrtf(Bv);
                int vlo = (int)ceilf(cvlo - 0.5f);   // first vv with vv+0.5 >= cvlo
                int vhi = (int)ceilf(cvhi - 0.5f);
                if (vhi > 512) vhi = 512;
                if (vlo < 0) vlo = 0;
                if (vhi > vlo) {
                    float hi = pref[vhi - 1] + cwx[(vhi - 1) >> 6];
                    float lo = (vlo > 0) ? (pref[vlo - 1] + cwx[(vlo - 1) >> 6]) : 0.0f;
                    acc += hi - lo;
                }
            }
        }
        __syncthreads();                      // before pref/cws overwrite next row
    }
    // per-block partial; every slot written every call (re-poison safe)
    partial[(((size_t)g * PBX) + blockIdx.x) * 512 + t] = acc;
}

// ---------------------------------------------------------------------------
// Fold partials -> rad  (block per image, 129 block-partials)
// ---------------------------------------------------------------------------
__global__ __launch_bounds__(512)
void reduce_partials(const float* __restrict__ partial, float* __restrict__ rad) {
    const int g = blockIdx.x;
    const int t = threadIdx.x;
    const float* p = partial + (size_t)g * PBX * 512;
    float s = 0.0f;
    for (int b = 0; b < PBX; ++b) s += p[(size_t)b * 512 + t];
    rad[(size_t)g * 512 + t] = s;
}

// ---------------------------------------------------------------------------
// Final: loss = mean(|rad_out - rad_tgt|) / S^2
// ---------------------------------------------------------------------------
__global__ __launch_bounds__(256)
void final_loss(const float* __restrict__ rad, float* __restrict__ out) {
    __shared__ float red[256];
    const int t = threadIdx.x;
    float acc = 0.0f;
    for (int i = t; i < 16 * RADIUS; i += 256) {
        int bb = i >> 9;
        int rr = i & (RADIUS - 1);
        float o = rad[(size_t)bb * RADIUS + rr];
        float gg = rad[(size_t)(bb + 16) * RADIUS + rr];
        acc += fabsf(o - gg);
    }
    red[t] = acc;
    __syncthreads();
    for (int off = 128; off > 0; off >>= 1) {
        if (t < off) red[t] += red[t + off];
        __syncthreads();
    }
    if (t == 0) {
        out[0] = red[0] / ((float)S * (float)S) / (16.0f * (float)RADIUS);
    }
}

extern "C" void kernel_launch(void* const* d_in, const int* in_sizes, int n_in,
                              void* d_out, int out_size, void* d_ws, size_t ws_size,
                              hipStream_t stream) {
    const float* outp = (const float*)d_in[0];
    const float* tgtp = (const float*)d_in[1];
    float* dout = (float*)d_out;

    char* ws = (char*)d_ws;
    float* rad = (float*)ws;                                       // 64 KB
    const size_t partBytes = (size_t)NIMG * PBX * 512 * sizeof(float);  // 8.45 MB
    float* partial = (float*)(ws + 65536);
    float2* WpT = (float2*)(ws + 65536 + partBytes);
    const size_t perImg = (size_t)512 * 1024 * sizeof(float2);     // 4 MB / image
    size_t used = 65536 + partBytes;
    size_t avail = (ws_size > used) ? (ws_size - used) : 0;
    int chunk = (int)(avail / perImg);
    if (chunk > NIMG) chunk = NIMG;
    if (chunk < 1) chunk = 1;

    for (int base = 0; base < NIMG; base += chunk) {
        int c = (NIMG - base < chunk) ? (NIMG - base) : chunk;
        fft_rows<<<dim3(64, c), 512, 0, stream>>>(outp, tgtp, WpT, base);
        fft_cols_bin2<<<dim3(PBX, c), 512, 0, stream>>>(WpT, partial, base);
    }

    reduce_partials<<<NIMG, 512, 0, stream>>>(partial, rad);
    final_loss<<<1, 256, 0, stream>>>(rad, dout);
}